// Round 3
// baseline (208.009 us; speedup 1.0000x reference)
//
#include <hip/hip_runtime.h>

// ExLlama q4: T=32, K=8192, N=28672, group=128.
// Harness promotes fp16 reference arrays to float32; output is float32.
//
// ROUND-3: ~132 us of dur is fixed harness ws-poison overhead (proven r1);
// only kernel time matters. Round-0 structure (split-16, stage-x-once, ONE
// barrier/block, register qweight prefetch, 4 cols/lane) measured ~55 us
// vs round-2's 8-barrier depth-1 pipeline at 71 us (87% stall: per-phase
// vmcnt(0) drains). This version = round-0 structure with a VGPR diet:
// qweight prefetched one group at a time into a 2-group double buffer
// (32 VGPRs instead of 64); group g+1's register loads are covered by
// group g's ~650-cyc compute via compiler counted-vmcnt waits (no barrier
// needed for register loads). Raw scales/zeros load before x staging,
// convert after. Target VGPR <= 128 -> 4 waves/SIMD (vs ~2-3), so the
// single prologue drain + epilogue tail get filled by TLP.
// Verified pieces kept bit-identical: 0x6400 nibble dequant, pkrtz
// pair-permuted x staging, MFMA 16x16x32 f16 fragment mapping, ws+reduce
// epilogue (ws poison is free).
#define T_TOK   32
#define KDIM    8192
#define NDIM    28672
#define NZW     3584             // N / 8
#define NSEG    16               // K-segments (blockIdx.y)
#define SEGK    (KDIM / NSEG)    // 512
#define GPS     (NSEG == 16 ? 4 : 4)  // groups per segment: SEGK/128 = 4
#define XROW    (SEGK + 8)       // padded LDS row stride (halves): 520
#define XIT     ((T_TOK * SEGK) / (256 * 8))   // 8 staging iters/thread

typedef _Float16 half8  __attribute__((ext_vector_type(8)));
typedef _Float16 half2v __attribute__((ext_vector_type(2)));
typedef float    f32x4  __attribute__((ext_vector_type(4)));
typedef unsigned uint4v __attribute__((ext_vector_type(4)));

template<bool ATOMIC>
__global__ __launch_bounds__(256)
void exllama_gemm16(const int*   __restrict__ qweight,
                    const int*   __restrict__ qzeros,
                    const float* __restrict__ scales,
                    const float* __restrict__ x,
                    const float* __restrict__ bias,
                    float*       __restrict__ ws,
                    float*       __restrict__ out)
{
    __shared__ alignas(16) _Float16 xs[T_TOK * XROW];   // 33.3 KB

    const int tid  = threadIdx.x;
    const int lane = tid & 63;
    const int wav  = tid >> 6;
    const int quad = lane >> 4;
    const int l16  = lane & 15;
    const int seg  = blockIdx.y;
    const int n0   = blockIdx.x * 256 + wav * 64;
    const int g0   = seg * GPS;

    int nc[4];
    #pragma unroll
    for (int j = 0; j < 4; ++j) nc[j] = n0 + j * 16 + l16;

    // ---- group-g qweight tile -> 16 registers (issued early, waited at use)
    auto LOADQW = [&](unsigned* qw, int g) {
        const size_t rb = (size_t)((g0 + g) * 16 + quad) * NDIM;
        #pragma unroll
        for (int c = 0; c < 4; ++c)
            #pragma unroll
            for (int j = 0; j < 4; ++j)
                qw[c * 4 + j] = (unsigned)qweight[rb + (size_t)(c * 4) * NDIM + nc[j]];
    };

    unsigned qwA[16], qwB[16];
    LOADQW(qwA, 0);                       // group 0 in flight before staging

    // ---- raw scales/zeros for all 4 groups (loads only; convert later) ----
    float sraw[GPS][4];
    int   zraw[GPS][4];
    #pragma unroll
    for (int g = 0; g < GPS; ++g)
        #pragma unroll
        for (int j = 0; j < 4; ++j) {
            sraw[g][j] = scales[(size_t)(g0 + g) * NDIM + nc[j]];
            zraw[g][j] = qzeros[(size_t)(g0 + g) * NZW + (nc[j] >> 3)];
        }

    // ---- stage x segment into LDS as fp16, pair-permuted [i, i+4] ----
    {
        const int kseg0 = seg * SEGK;
        #pragma unroll
        for (int it = 0; it < XIT; ++it) {               // 8 iters
            const int e  = it * 2048 + tid * 8;
            const int t  = e >> 9;                       // SEGK = 512
            const int kl = e & (SEGK - 1);
            const float* xp = x + (size_t)t * KDIM + kseg0 + kl;
            f32x4 lo = *(const f32x4*)xp;
            f32x4 hi = *(const f32x4*)(xp + 4);
            uint4v u;
            #pragma unroll
            for (int j = 0; j < 4; ++j)
                u[j] = __builtin_bit_cast(unsigned,
                          __builtin_amdgcn_cvt_pkrtz(lo[j], hi[j]));
            *(uint4v*)(xs + t * XROW + kl) = u;
        }
    }

    // ---- convert scales/zeros (loads landed long ago; no stall) ----
    half2v sp[GPS][4], cp[GPS][4];
    #pragma unroll
    for (int g = 0; g < GPS; ++g)
        #pragma unroll
        for (int j = 0; j < 4; ++j) {
            const int z = (zraw[g][j] >> ((nc[j] & 7) * 4)) & 15;
            const _Float16 sh = (_Float16)sraw[g][j];
            const _Float16 ch = (_Float16)(float)(-(1025 + z));
            sp[g][j] = (half2v){sh, sh};
            cp[g][j] = (half2v){ch, ch};
        }

    __syncthreads();                       // the ONLY barrier in this kernel

    f32x4 acc[4][2];
    #pragma unroll
    for (int j = 0; j < 4; ++j)
        #pragma unroll
        for (int m = 0; m < 2; ++m)
            acc[j][m] = (f32x4){0.f, 0.f, 0.f, 0.f};

    auto COMPUTEG = [&](const unsigned* qw, int g) {
        #pragma unroll
        for (int c = 0; c < 4; ++c) {
            const int kloc = g * 128 + c * 32 + quad * 8;
            half8 a0 = *(const half8*)(xs + l16 * XROW + kloc);
            half8 a1 = *(const half8*)(xs + (l16 + 16) * XROW + kloc);
            #pragma unroll
            for (int j = 0; j < 4; ++j) {
                const unsigned w = qw[c * 4 + j];
                uint4v bu;
                #pragma unroll
                for (int i = 0; i < 4; ++i) {
                    unsigned t = ((w >> (4 * i)) & 0x000F000Fu) | 0x64006400u;
                    half2v th = __builtin_bit_cast(half2v, t);
                    half2v r  = (th + cp[g][j]) * sp[g][j];
                    bu[i] = __builtin_bit_cast(unsigned, r);
                }
                half8 bf = __builtin_bit_cast(half8, bu);
                acc[j][0] = __builtin_amdgcn_mfma_f32_16x16x32_f16(a0, bf, acc[j][0], 0, 0, 0);
                acc[j][1] = __builtin_amdgcn_mfma_f32_16x16x32_f16(a1, bf, acc[j][1], 0, 0, 0);
            }
        }
    };

    // ---- compute: qweight double-buffered one group deep ----
    LOADQW(qwB, 1);        // in flight during group-0 compute
    COMPUTEG(qwA, 0);
    LOADQW(qwA, 2);        // reuses qwA after its last read
    COMPUTEG(qwB, 1);
    LOADQW(qwB, 3);
    COMPUTEG(qwA, 2);
    COMPUTEG(qwB, 3);

    // ---- epilogue ----
    if (ATOMIC) {
        #pragma unroll
        for (int j = 0; j < 4; ++j) {
            const float bb = bias[nc[j]] * (1.0f / NSEG);
            #pragma unroll
            for (int m = 0; m < 2; ++m)
                #pragma unroll
                for (int r = 0; r < 4; ++r) {
                    const int t = m * 16 + quad * 4 + r;
                    unsafeAtomicAdd(out + (size_t)t * NDIM + nc[j], acc[j][m][r] + bb);
                }
        }
    } else {
        float* wsp = ws + (size_t)seg * (T_TOK * NDIM);
        #pragma unroll
        for (int j = 0; j < 4; ++j)
            #pragma unroll
            for (int m = 0; m < 2; ++m)
                #pragma unroll
                for (int r = 0; r < 4; ++r) {
                    const int t = m * 16 + quad * 4 + r;
                    wsp[(size_t)t * NDIM + nc[j]] = acc[j][m][r];
                }
    }
}

__global__ __launch_bounds__(256)
void reduce_bias(const float* __restrict__ ws,
                 const float* __restrict__ bias,
                 float*       __restrict__ out)
{
    const int e = (blockIdx.x * 256 + threadIdx.x) * 4;  // 4 consecutive, one row
    const int n = e % NDIM;
    f32x4 sum = (f32x4){0.f, 0.f, 0.f, 0.f};
    #pragma unroll
    for (int s = 0; s < NSEG; ++s)
        sum += *(const f32x4*)(ws + (size_t)s * (T_TOK * NDIM) + e);
    f32x4 bb = *(const f32x4*)(bias + n);
    *(f32x4*)(out + e) = sum + bb;
}

extern "C" void kernel_launch(void* const* d_in, const int* in_sizes, int n_in,
                              void* d_out, int out_size, void* d_ws, size_t ws_size,
                              hipStream_t stream)
{
    const float* x  = (const float*)d_in[0];   // (32, 8192) f32 (fp16 promoted)
    const int* qweight = (const int*)d_in[1];  // (1024, 28672) i32
    const int* qzeros  = (const int*)d_in[2];  // (64, 3584) i32
    const float* sc = (const float*)d_in[3];   // (64, 28672) f32
    const float* bs = (const float*)d_in[4];   // (28672,) f32
    float* out      = (float*)d_out;           // (32, 28672) f32

    const size_t need = (size_t)NSEG * T_TOK * NDIM * sizeof(float);  // 58.7 MB
    if (ws_size >= need) {
        exllama_gemm16<false><<<dim3(NDIM / 256, NSEG), 256, 0, stream>>>(
            qweight, qzeros, sc, x, bs, (float*)d_ws, out);
        reduce_bias<<<(T_TOK * NDIM) / (256 * 4), 256, 0, stream>>>(
            (const float*)d_ws, bs, out);
    } else {
        exllama_gemm16<true><<<dim3(NDIM / 256, NSEG), 256, 0, stream>>>(
            qweight, qzeros, sc, x, bs, nullptr, out);
    }
}